// Round 2
// baseline (448.009 us; speedup 1.0000x reference)
//
#include <hip/hip_runtime.h>
#include <hip/hip_bf16.h>

#define D 128           // D_IN == D_OUT == 128
#define NBLK 1024       // persistent grid: 4 blocks/CU x 256 CUs, guaranteed co-resident
#define GEMM_ROWS 32    // fallback tier only

typedef __bf16 bf16x8 __attribute__((ext_vector_type(8)));
typedef float  f32x4  __attribute__((ext_vector_type(4)));
typedef unsigned int u32x4 __attribute__((ext_vector_type(4)));

__device__ inline bf16x8 cvt_a8(const float* __restrict__ p) {
    float4 v0 = ((const float4*)p)[0], v1 = ((const float4*)p)[1];
    bf16x8 a;
    a[0] = (__bf16)v0.x; a[1] = (__bf16)v0.y; a[2] = (__bf16)v0.z; a[3] = (__bf16)v0.w;
    a[4] = (__bf16)v1.x; a[5] = (__bf16)v1.y; a[6] = (__bf16)v1.z; a[7] = (__bf16)v1.w;
    return a;
}

// ---------------------------------------------------------------------------
// Fully-fused persistent kernel:
//   Phase A1: bf16 MFMA GEMM h = x@w over grid-strided 64-row tiles
//   Phase A2: row_ptr build from sorted COO rows
//   software grid barrier (all 1024 blocks co-resident by __launch_bounds__)
//   Phase B : SpMM batch-4 gathers, one contiguous ~13-row chunk per wave
// Removes the K1->K2 dispatch boundary and makes the kernel long enough
// (>47us) to surface in rocprof top-5 with full counters.
// ---------------------------------------------------------------------------
__global__ __launch_bounds__(256, 4) void gcn_fused(
        const float* __restrict__ x, const float* __restrict__ w,
        const int* __restrict__ rows, const int* __restrict__ cols,
        const float* __restrict__ vals,
        unsigned short* __restrict__ h, int* __restrict__ rp,
        int* __restrict__ cnt, float* __restrict__ out,
        int n_nodes, int n_edges) {
    const int b    = blockIdx.x;
    const int tid  = threadIdx.x;
    const int wave = tid >> 6;
    const int lane = tid & 63;
    const int m16  = lane & 15;
    const int q    = lane >> 4;

    // ---------------- Phase A1: GEMM tiles (grid-strided) ----------------
    const int n_pad = (n_nodes + 63) & ~63;
    const int tiles = n_pad >> 6;
    const int col0  = wave * 32;

    if (b < tiles) {
        // w fragments loaded ONCE per wave (hoisted out of the tile loop)
        bf16x8 bfr[2][4];
#pragma unroll
        for (int t = 0; t < 2; ++t)
#pragma unroll
            for (int s = 0; s < 4; ++s) {
                const float* wp = w + (size_t)(32 * s + q * 8) * D + col0 + 16 * t + m16;
#pragma unroll
                for (int j = 0; j < 8; ++j)
                    bfr[t][s][j] = (__bf16)wp[(size_t)j * D];
            }

        for (int tile = b; tile < tiles; tile += NBLK) {
            const int row0 = tile * 64;
#pragma unroll 1
            for (int sl = 0; sl < 4; ++sl) {
                const int r = row0 + sl * 16 + m16;
                const float* xp = x + (size_t)r * D + q * 8;

                bf16x8 a[4];
                if (r < n_nodes) {
#pragma unroll
                    for (int s = 0; s < 4; ++s) a[s] = cvt_a8(xp + 32 * s);
                } else {
#pragma unroll
                    for (int s = 0; s < 4; ++s)
#pragma unroll
                        for (int j = 0; j < 8; ++j) a[s][j] = (__bf16)0.f;
                }

                f32x4 acc0 = (f32x4)0.f, acc1 = (f32x4)0.f;
#pragma unroll
                for (int s = 0; s < 4; ++s) {
                    acc0 = __builtin_amdgcn_mfma_f32_16x16x32_bf16(a[s], bfr[0][s], acc0, 0, 0, 0);
                    acc1 = __builtin_amdgcn_mfma_f32_16x16x32_bf16(a[s], bfr[1][s], acc1, 0, 0, 0);
                }

#pragma unroll
                for (int i = 0; i < 4; ++i) {
                    int row = row0 + sl * 16 + q * 4 + i;
                    h[(size_t)row * D + col0 + m16]      = __builtin_bit_cast(unsigned short, (__bf16)acc0[i]);
                    h[(size_t)row * D + col0 + 16 + m16] = __builtin_bit_cast(unsigned short, (__bf16)acc1[i]);
                }
            }
        }
    }

    // ---------------- Phase A2: row_ptr build (grid-strided) ----------------
    for (int e = b * 256 + tid; e < n_edges; e += NBLK * 256) {
        int r    = rows[e];
        int prev = (e == 0) ? -1 : rows[e - 1];
        for (int rr = prev + 1; rr <= r; ++rr) rp[rr] = e;
        if (e == n_edges - 1)
            for (int rr = r + 1; rr <= n_nodes; ++rr) rp[rr] = n_edges;
    }

    // ---------------- software grid barrier ----------------
    // agent-scope fence: writes of h/rp become visible across XCDs
    __threadfence();
    __syncthreads();
    if (tid == 0) {
        __hip_atomic_fetch_add(cnt, 1, __ATOMIC_ACQ_REL, __HIP_MEMORY_SCOPE_AGENT);
        while (__hip_atomic_load(cnt, __ATOMIC_ACQUIRE, __HIP_MEMORY_SCOPE_AGENT) < (int)gridDim.x)
            __builtin_amdgcn_s_sleep(2);
    }
    __syncthreads();
    __threadfence();

    // ---------------- Phase B: SpMM, batch-4 gathers ----------------
    const int wid   = b * 4 + wave;
    const int nw    = NBLK * 4;
    const int chunk = (n_nodes + nw - 1) / nw;      // contiguous rows per wave
    const int rbeg  = wid * chunk;
    const int rend  = (rbeg + chunk < n_nodes) ? rbeg + chunk : n_nodes;
    const int chain = lane >> 4;    // 4 edge chains, stride 4
    const int l4    = lane & 15;    // 16B slot: dims [l4*8, l4*8+8)
    const u32x4* h4 = (const u32x4*)h;

#define FMA8(hv, vv)                                                              \
    _Pragma("unroll")                                                             \
    for (int j = 0; j < 4; ++j) {                                                 \
        unsigned int u = (hv)[j];                                                 \
        acc[2 * j]     = fmaf((vv), __builtin_bit_cast(float, u << 16),           \
                              acc[2 * j]);                                        \
        acc[2 * j + 1] = fmaf((vv), __builtin_bit_cast(float, u & 0xFFFF0000u),   \
                              acc[2 * j + 1]);                                    \
    }

    for (int r = rbeg; r < rend; ++r) {
        const int start = rp[r];
        const int end   = rp[r + 1];

        float acc[8];
#pragma unroll
        for (int j = 0; j < 8; ++j) acc[j] = 0.f;

        int e = start + chain;
        int c0 = 0, c1 = 0, c2 = 0, c3 = 0;
        float v0 = 0.f, v1 = 0.f, v2 = 0.f, v3 = 0.f;
        if (e < end)      { c0 = cols[e];      v0 = vals[e]; }
        if (e + 4 < end)  { c1 = cols[e + 4];  v1 = vals[e + 4]; }
        if (e + 8 < end)  { c2 = cols[e + 8];  v2 = vals[e + 8]; }
        if (e + 12 < end) { c3 = cols[e + 12]; v3 = vals[e + 12]; }

        while (e < end) {
            int en = e + 16;
            int cn0 = 0, cn1 = 0, cn2 = 0, cn3 = 0;
            float vn0 = 0.f, vn1 = 0.f, vn2 = 0.f, vn3 = 0.f;
            if (en < end)      { cn0 = cols[en];      vn0 = vals[en]; }
            if (en + 4 < end)  { cn1 = cols[en + 4];  vn1 = vals[en + 4]; }
            if (en + 8 < end)  { cn2 = cols[en + 8];  vn2 = vals[en + 8]; }
            if (en + 12 < end) { cn3 = cols[en + 12]; vn3 = vals[en + 12]; }

            u32x4 hv0 = h4[(size_t)c0 * (D / 8) + l4];
            u32x4 hv1 = h4[(size_t)c1 * (D / 8) + l4];
            u32x4 hv2 = h4[(size_t)c2 * (D / 8) + l4];
            u32x4 hv3 = h4[(size_t)c3 * (D / 8) + l4];

            FMA8(hv0, v0)
            FMA8(hv1, v1)
            FMA8(hv2, v2)
            FMA8(hv3, v3)

            c0 = cn0; v0 = vn0; c1 = cn1; v1 = vn1;
            c2 = cn2; v2 = vn2; c3 = cn3; v3 = vn3;
            e = en;
        }

#pragma unroll
        for (int j = 0; j < 8; ++j) {
            acc[j] += __shfl_xor(acc[j], 16);
            acc[j] += __shfl_xor(acc[j], 32);
        }

        if (chain == 0) {
            float4 o0, o1;
            o0.x = fmaxf(acc[0], 0.f); o0.y = fmaxf(acc[1], 0.f);
            o0.z = fmaxf(acc[2], 0.f); o0.w = fmaxf(acc[3], 0.f);
            o1.x = fmaxf(acc[4], 0.f); o1.y = fmaxf(acc[5], 0.f);
            o1.z = fmaxf(acc[6], 0.f); o1.w = fmaxf(acc[7], 0.f);
            float4* op = (float4*)(out + (size_t)r * D + l4 * 8);
            op[0] = o0; op[1] = o1;
        }
    }
#undef FMA8
}

// ============================ fallback tiers ===============================
__global__ __launch_bounds__(256) void gemm128(const float* __restrict__ x,
                                               const float* __restrict__ w,
                                               float* __restrict__ h, int n) {
    __shared__ float4 ws4[D * D / 4];
    __shared__ float  xs[GEMM_ROWS][D];
    const int tid  = threadIdx.x;
    const int row0 = blockIdx.x * GEMM_ROWS;
    const float4* w4 = (const float4*)w;
    for (int i = tid; i < D * D / 4; i += 256) ws4[i] = w4[i];
    float4* xs4 = (float4*)&xs[0][0];
    const float4* x4 = (const float4*)x;
    for (int i = tid; i < GEMM_ROWS * D / 4; i += 256) {
        int row = row0 + (i >> 5);
        float4 v = make_float4(0.f, 0.f, 0.f, 0.f);
        if (row < n) v = x4[(size_t)row0 * (D / 4) + i];
        xs4[i] = v;
    }
    __syncthreads();
    const int tx = tid & 31, ty = tid >> 5;
    float4 acc[4];
#pragma unroll
    for (int i = 0; i < 4; ++i) acc[i] = make_float4(0.f, 0.f, 0.f, 0.f);
#pragma unroll 8
    for (int k = 0; k < D; ++k) {
        float4 wv = ws4[k * (D / 4) + tx];
#pragma unroll
        for (int i = 0; i < 4; ++i) {
            float xv = xs[ty * 4 + i][k];
            acc[i].x = fmaf(xv, wv.x, acc[i].x);
            acc[i].y = fmaf(xv, wv.y, acc[i].y);
            acc[i].z = fmaf(xv, wv.z, acc[i].z);
            acc[i].w = fmaf(xv, wv.w, acc[i].w);
        }
    }
#pragma unroll
    for (int i = 0; i < 4; ++i) {
        int row = row0 + ty * 4 + i;
        if (row < n) ((float4*)(h + (size_t)row * D))[tx] = acc[i];
    }
}

__global__ __launch_bounds__(128) void spmm_row(const float* __restrict__ h,
                                                const int* __restrict__ rows,
                                                const int* __restrict__ cols,
                                                const float* __restrict__ vals,
                                                float* __restrict__ out, int n_edges) {
    const int r = blockIdx.x, d = threadIdx.x;
    int lo = 0, hi = n_edges;
    while (lo < hi) { int m = (lo + hi) >> 1; if (rows[m] < r) lo = m + 1; else hi = m; }
    const int start = lo;
    hi = n_edges;
    while (lo < hi) { int m = (lo + hi) >> 1; if (rows[m] <= r) lo = m + 1; else hi = m; }
    const int end = lo;
    float acc = 0.f;
    for (int e = start; e < end; ++e)
        acc = fmaf(vals[e], h[(size_t)cols[e] * D + d], acc);
    out[(size_t)r * D + d] = fmaxf(acc, 0.f);
}

__global__ __launch_bounds__(128) void fused_fallback(
        const float* __restrict__ x, const float* __restrict__ w,
        const int* __restrict__ rows, const int* __restrict__ cols,
        const float* __restrict__ vals, float* __restrict__ out, int n_edges) {
    const int r = blockIdx.x, d = threadIdx.x;
    int lo = 0, hi = n_edges;
    while (lo < hi) { int m = (lo + hi) >> 1; if (rows[m] < r) lo = m + 1; else hi = m; }
    const int start = lo;
    hi = n_edges;
    while (lo < hi) { int m = (lo + hi) >> 1; if (rows[m] <= r) lo = m + 1; else hi = m; }
    const int end = lo;
    float acc = 0.f;
    for (int e = start; e < end; ++e) {
        int c = cols[e]; float v = vals[e];
        float hcd = 0.f;
        for (int k = 0; k < D; ++k)
            hcd = fmaf(x[(size_t)c * D + k], w[(size_t)k * D + d], hcd);
        acc = fmaf(v, hcd, acc);
    }
    out[(size_t)r * D + d] = fmaxf(acc, 0.f);
}

// ===========================================================================
extern "C" void kernel_launch(void* const* d_in, const int* in_sizes, int n_in,
                              void* d_out, int out_size, void* d_ws, size_t ws_size,
                              hipStream_t stream) {
    const float* x    = (const float*)d_in[0];
    const float* w    = (const float*)d_in[1];
    const int*   rows = (const int*)d_in[2];
    const int*   cols = (const int*)d_in[3];
    const float* vals = (const float*)d_in[4];
    float* out = (float*)d_out;

    const int n_nodes = in_sizes[0] / D;              // 50000
    const int n_edges = in_sizes[2];                  // 800000
    const int n_pad   = (n_nodes + 63) & ~63;         // 50048

    const size_t h_bytes  = (size_t)n_pad * D * sizeof(unsigned short);  // 12.8 MB
    const size_t rp_off   = h_bytes;
    const size_t cnt_off  = rp_off + (size_t)(n_nodes + 1) * sizeof(int);
    const size_t need     = cnt_off + sizeof(int);
    const size_t hf_bytes = (size_t)n_nodes * D * sizeof(float);

    if (ws_size >= need) {
        unsigned short* h  = (unsigned short*)d_ws;
        int*            rp = (int*)((char*)d_ws + rp_off);
        int*            cnt = (int*)((char*)d_ws + cnt_off);

        // barrier counter must be zero before every replay
        hipMemsetAsync(cnt, 0, sizeof(int), stream);

        gcn_fused<<<NBLK, 256, 0, stream>>>(x, w, rows, cols, vals,
                                            h, rp, cnt, out, n_nodes, n_edges);
    } else if (ws_size >= hf_bytes) {
        float* hf = (float*)d_ws;
        gemm128<<<(n_nodes + GEMM_ROWS - 1) / GEMM_ROWS, 256, 0, stream>>>(x, w, hf, n_nodes);
        spmm_row<<<n_nodes, 128, 0, stream>>>(hf, rows, cols, vals, out, n_edges);
    } else {
        fused_fallback<<<n_nodes, 128, 0, stream>>>(x, w, rows, cols, vals, out, n_edges);
    }
}

// Round 3
// 133.694 us; speedup vs baseline: 3.3510x; 3.3510x over previous
//
#include <hip/hip_runtime.h>
#include <hip/hip_bf16.h>

#define D 128           // D_IN == D_OUT == 128
#define GEMM_ROWS 32    // fallback tier only

typedef __bf16 bf16x8 __attribute__((ext_vector_type(8)));
typedef float  f32x4  __attribute__((ext_vector_type(4)));
typedef unsigned int u32x4 __attribute__((ext_vector_type(4)));

// ---------------------------------------------------------------------------
// K1: fused GEMM + row_ptr. R3 delta vs R1: x loaded NON-TEMPORAL (streamed
// exactly once, no reuse) so it does not evict the freshly-written h lines
// from per-XCD L2 -- h is K2's gather working set.
// ---------------------------------------------------------------------------
__device__ inline bf16x8 cvt_a8_nt(const float* __restrict__ p) {
    f32x4 v0 = __builtin_nontemporal_load((const f32x4*)p);
    f32x4 v1 = __builtin_nontemporal_load(((const f32x4*)p) + 1);
    bf16x8 a;
    a[0] = (__bf16)v0[0]; a[1] = (__bf16)v0[1]; a[2] = (__bf16)v0[2]; a[3] = (__bf16)v0[3];
    a[4] = (__bf16)v1[0]; a[5] = (__bf16)v1[1]; a[6] = (__bf16)v1[2]; a[7] = (__bf16)v1[3];
    return a;
}

__global__ __launch_bounds__(256) void fused_gemm_rp(
        const float* __restrict__ x, const float* __restrict__ w,
        const int* __restrict__ rows,
        unsigned short* __restrict__ h, int* __restrict__ rp,
        int n_nodes, int n_edges, int gemm_blocks) {
    const int b = blockIdx.x;

    if (b >= gemm_blocks) {           // ---- row_ptr builder blocks ----
        int e = (b - gemm_blocks) * 256 + threadIdx.x;
        if (e >= n_edges) return;
        int r    = rows[e];
        int prev = (e == 0) ? -1 : rows[e - 1];
        for (int rr = prev + 1; rr <= r; ++rr) rp[rr] = e;
        if (e == n_edges - 1)
            for (int rr = r + 1; rr <= n_nodes; ++rr) rp[rr] = n_edges;
        return;
    }

    const int wave = threadIdx.x >> 6;
    const int lane = threadIdx.x & 63;
    const int m16  = lane & 15;
    const int q    = lane >> 4;

    const int row0 = b * 64;
    const int col0 = wave * 32;

    // w is reused by every block: keep it cached (NO nt).
    bf16x8 bfr[2][4];
#pragma unroll
    for (int t = 0; t < 2; ++t)
#pragma unroll
        for (int s = 0; s < 4; ++s) {
            const float* wp = w + (size_t)(32 * s + q * 8) * D + col0 + 16 * t + m16;
#pragma unroll
            for (int j = 0; j < 8; ++j)
                bfr[t][s][j] = (__bf16)wp[(size_t)j * D];
        }

#pragma unroll 1
    for (int sl = 0; sl < 4; ++sl) {
        const int r = row0 + sl * 16 + m16;
        const float* xp = x + (size_t)r * D + q * 8;

        bf16x8 a[4];
        if (r < n_nodes) {
#pragma unroll
            for (int s = 0; s < 4; ++s) a[s] = cvt_a8_nt(xp + 32 * s);
        } else {
#pragma unroll
            for (int s = 0; s < 4; ++s)
#pragma unroll
                for (int j = 0; j < 8; ++j) a[s][j] = (__bf16)0.f;
        }

        f32x4 acc0 = (f32x4)0.f, acc1 = (f32x4)0.f;
#pragma unroll
        for (int s = 0; s < 4; ++s) {
            acc0 = __builtin_amdgcn_mfma_f32_16x16x32_bf16(a[s], bfr[0][s], acc0, 0, 0, 0);
            acc1 = __builtin_amdgcn_mfma_f32_16x16x32_bf16(a[s], bfr[1][s], acc1, 0, 0, 0);
        }

        // h stores stay CACHED: h is K2's gather table.
#pragma unroll
        for (int i = 0; i < 4; ++i) {
            int row = row0 + sl * 16 + q * 4 + i;
            h[(size_t)row * D + col0 + m16]      = __builtin_bit_cast(unsigned short, (__bf16)acc0[i]);
            h[(size_t)row * D + col0 + 16 + m16] = __builtin_bit_cast(unsigned short, (__bf16)acc1[i]);
        }
    }
}

// ---------------------------------------------------------------------------
// K2: SpMM on bf16 h — R5 structure (4 chains x 16 lanes x 16B) with BATCH-4
// gathers. R3 delta vs R1: cols/vals loads and out stores are NON-TEMPORAL
// (single-touch streams) so per-XCD L2 capacity is reserved for h gather
// lines; out write-allocate traffic bypasses L2 entirely.
// ---------------------------------------------------------------------------
#define FMA8(hv, vv)                                                              \
    _Pragma("unroll")                                                             \
    for (int j = 0; j < 4; ++j) {                                                 \
        unsigned int u = (hv)[j];                                                 \
        acc[2 * j]     = fmaf((vv), __builtin_bit_cast(float, u << 16),           \
                              acc[2 * j]);                                        \
        acc[2 * j + 1] = fmaf((vv), __builtin_bit_cast(float, u & 0xFFFF0000u),   \
                              acc[2 * j + 1]);                                    \
    }

__global__ __launch_bounds__(256) void spmm_bf16_b4(
        const unsigned short* __restrict__ h,
        const int* __restrict__ row_ptr,
        const int* __restrict__ cols,
        const float* __restrict__ vals,
        float* __restrict__ out, int n) {
    const int wave = threadIdx.x >> 6;
    const int lane = threadIdx.x & 63;
    const int r = blockIdx.x * 4 + wave;
    if (r >= n) return;

    const int start = row_ptr[r];
    const int end   = row_ptr[r + 1];
    const int chain = lane >> 4;    // 4 edge chains, stride 4
    const int l4    = lane & 15;    // 16B slot: dims [l4*8, l4*8+8)

    const u32x4* h4 = (const u32x4*)h;
    float acc[8];
#pragma unroll
    for (int j = 0; j < 8; ++j) acc[j] = 0.f;

    int e = start + chain;
    int c0 = 0, c1 = 0, c2 = 0, c3 = 0;
    float v0 = 0.f, v1 = 0.f, v2 = 0.f, v3 = 0.f;
    if (e < end)      { c0 = __builtin_nontemporal_load(cols + e);      v0 = __builtin_nontemporal_load(vals + e); }
    if (e + 4 < end)  { c1 = __builtin_nontemporal_load(cols + e + 4);  v1 = __builtin_nontemporal_load(vals + e + 4); }
    if (e + 8 < end)  { c2 = __builtin_nontemporal_load(cols + e + 8);  v2 = __builtin_nontemporal_load(vals + e + 8); }
    if (e + 12 < end) { c3 = __builtin_nontemporal_load(cols + e + 12); v3 = __builtin_nontemporal_load(vals + e + 12); }

    while (e < end) {
        // prefetch next batch's indices (overlaps the four gathers below)
        int en = e + 16;
        int cn0 = 0, cn1 = 0, cn2 = 0, cn3 = 0;
        float vn0 = 0.f, vn1 = 0.f, vn2 = 0.f, vn3 = 0.f;
        if (en < end)      { cn0 = __builtin_nontemporal_load(cols + en);      vn0 = __builtin_nontemporal_load(vals + en); }
        if (en + 4 < end)  { cn1 = __builtin_nontemporal_load(cols + en + 4);  vn1 = __builtin_nontemporal_load(vals + en + 4); }
        if (en + 8 < end)  { cn2 = __builtin_nontemporal_load(cols + en + 8);  vn2 = __builtin_nontemporal_load(vals + en + 8); }
        if (en + 12 < end) { cn3 = __builtin_nontemporal_load(cols + en + 12); vn3 = __builtin_nontemporal_load(vals + en + 12); }

        // all four gathers in flight before any is consumed (h stays cached)
        u32x4 hv0 = h4[(size_t)c0 * (D / 8) + l4];
        u32x4 hv1 = h4[(size_t)c1 * (D / 8) + l4];
        u32x4 hv2 = h4[(size_t)c2 * (D / 8) + l4];
        u32x4 hv3 = h4[(size_t)c3 * (D / 8) + l4];

        FMA8(hv0, v0)
        FMA8(hv1, v1)
        FMA8(hv2, v2)
        FMA8(hv3, v3)

        c0 = cn0; v0 = vn0; c1 = cn1; v1 = vn1;
        c2 = cn2; v2 = vn2; c3 = cn3; v3 = vn3;
        e = en;
    }

    // combine 4 chains (chain index in lane bits 4,5)
#pragma unroll
    for (int j = 0; j < 8; ++j) {
        acc[j] += __shfl_xor(acc[j], 16);
        acc[j] += __shfl_xor(acc[j], 32);
    }

    if (chain == 0) {
        f32x4 o0, o1;
        o0[0] = fmaxf(acc[0], 0.f); o0[1] = fmaxf(acc[1], 0.f);
        o0[2] = fmaxf(acc[2], 0.f); o0[3] = fmaxf(acc[3], 0.f);
        o1[0] = fmaxf(acc[4], 0.f); o1[1] = fmaxf(acc[5], 0.f);
        o1[2] = fmaxf(acc[6], 0.f); o1[3] = fmaxf(acc[7], 0.f);
        f32x4* op = (f32x4*)(out + (size_t)r * D + l4 * 8);
        __builtin_nontemporal_store(o0, op);
        __builtin_nontemporal_store(o1, op + 1);
    }
}

// ============================ fallback tiers ===============================
__global__ __launch_bounds__(256) void gemm128(const float* __restrict__ x,
                                               const float* __restrict__ w,
                                               float* __restrict__ h, int n) {
    __shared__ float4 ws4[D * D / 4];
    __shared__ float  xs[GEMM_ROWS][D];
    const int tid  = threadIdx.x;
    const int row0 = blockIdx.x * GEMM_ROWS;
    const float4* w4 = (const float4*)w;
    for (int i = tid; i < D * D / 4; i += 256) ws4[i] = w4[i];
    float4* xs4 = (float4*)&xs[0][0];
    const float4* x4 = (const float4*)x;
    for (int i = tid; i < GEMM_ROWS * D / 4; i += 256) {
        int row = row0 + (i >> 5);
        float4 v = make_float4(0.f, 0.f, 0.f, 0.f);
        if (row < n) v = x4[(size_t)row0 * (D / 4) + i];
        xs4[i] = v;
    }
    __syncthreads();
    const int tx = tid & 31, ty = tid >> 5;
    float4 acc[4];
#pragma unroll
    for (int i = 0; i < 4; ++i) acc[i] = make_float4(0.f, 0.f, 0.f, 0.f);
#pragma unroll 8
    for (int k = 0; k < D; ++k) {
        float4 wv = ws4[k * (D / 4) + tx];
#pragma unroll
        for (int i = 0; i < 4; ++i) {
            float xv = xs[ty * 4 + i][k];
            acc[i].x = fmaf(xv, wv.x, acc[i].x);
            acc[i].y = fmaf(xv, wv.y, acc[i].y);
            acc[i].z = fmaf(xv, wv.z, acc[i].z);
            acc[i].w = fmaf(xv, wv.w, acc[i].w);
        }
    }
#pragma unroll
    for (int i = 0; i < 4; ++i) {
        int row = row0 + ty * 4 + i;
        if (row < n) ((float4*)(h + (size_t)row * D))[tx] = acc[i];
    }
}

__global__ __launch_bounds__(128) void spmm_row(const float* __restrict__ h,
                                                const int* __restrict__ rows,
                                                const int* __restrict__ cols,
                                                const float* __restrict__ vals,
                                                float* __restrict__ out, int n_edges) {
    const int r = blockIdx.x, d = threadIdx.x;
    int lo = 0, hi = n_edges;
    while (lo < hi) { int m = (lo + hi) >> 1; if (rows[m] < r) lo = m + 1; else hi = m; }
    const int start = lo;
    hi = n_edges;
    while (lo < hi) { int m = (lo + hi) >> 1; if (rows[m] <= r) lo = m + 1; else hi = m; }
    const int end = lo;
    float acc = 0.f;
    for (int e = start; e < end; ++e)
        acc = fmaf(vals[e], h[(size_t)cols[e] * D + d], acc);
    out[(size_t)r * D + d] = fmaxf(acc, 0.f);
}

__global__ __launch_bounds__(128) void fused_fallback(
        const float* __restrict__ x, const float* __restrict__ w,
        const int* __restrict__ rows, const int* __restrict__ cols,
        const float* __restrict__ vals, float* __restrict__ out, int n_edges) {
    const int r = blockIdx.x, d = threadIdx.x;
    int lo = 0, hi = n_edges;
    while (lo < hi) { int m = (lo + hi) >> 1; if (rows[m] < r) lo = m + 1; else hi = m; }
    const int start = lo;
    hi = n_edges;
    while (lo < hi) { int m = (lo + hi) >> 1; if (rows[m] <= r) lo = m + 1; else hi = m; }
    const int end = lo;
    float acc = 0.f;
    for (int e = start; e < end; ++e) {
        int c = cols[e]; float v = vals[e];
        float hcd = 0.f;
        for (int k = 0; k < D; ++k)
            hcd = fmaf(x[(size_t)c * D + k], w[(size_t)k * D + d], hcd);
        acc = fmaf(v, hcd, acc);
    }
    out[(size_t)r * D + d] = fmaxf(acc, 0.f);
}

// ===========================================================================
extern "C" void kernel_launch(void* const* d_in, const int* in_sizes, int n_in,
                              void* d_out, int out_size, void* d_ws, size_t ws_size,
                              hipStream_t stream) {
    const float* x    = (const float*)d_in[0];
    const float* w    = (const float*)d_in[1];
    const int*   rows = (const int*)d_in[2];
    const int*   cols = (const int*)d_in[3];
    const float* vals = (const float*)d_in[4];
    float* out = (float*)d_out;

    const int n_nodes = in_sizes[0] / D;              // 50000
    const int n_edges = in_sizes[2];                  // 800000
    const int n_pad   = (n_nodes + 63) & ~63;         // 50048

    const size_t h_bytes  = (size_t)n_pad * D * sizeof(unsigned short);  // 12.8 MB
    const size_t rp_off   = h_bytes;
    const size_t need     = rp_off + (size_t)(n_nodes + 1) * sizeof(int);
    const size_t hf_bytes = (size_t)n_nodes * D * sizeof(float);

    if (ws_size >= need) {
        unsigned short* h  = (unsigned short*)d_ws;
        int*            rp = (int*)((char*)d_ws + rp_off);

        const int gemm_blocks = n_pad / 64;                      // 782
        const int rp_blocks   = (n_edges + 255) / 256;           // 3125
        fused_gemm_rp<<<gemm_blocks + rp_blocks, 256, 0, stream>>>(
            x, w, rows, h, rp, n_nodes, n_edges, gemm_blocks);

        spmm_bf16_b4<<<(n_nodes + 3) / 4, 256, 0, stream>>>(h, rp, cols, vals, out, n_nodes);
    } else if (ws_size >= hf_bytes) {
        float* hf = (float*)d_ws;
        gemm128<<<(n_nodes + GEMM_ROWS - 1) / GEMM_ROWS, 256, 0, stream>>>(x, w, hf, n_nodes);
        spmm_row<<<n_nodes, 128, 0, stream>>>(hf, rows, cols, vals, out, n_edges);
    } else {
        fused_fallback<<<n_nodes, 128, 0, stream>>>(x, w, rows, cols, vals, out, n_edges);
    }
}